// Round 3
// baseline (143.784 us; speedup 1.0000x reference)
//
#include <hip/hip_runtime.h>

#define BATCH 262144
#define HID 64
#define NSTEP 50

// One thread per batch element, t-outer / h-inner.
// Round-3 change: __launch_bounds__(256, 1). Round 2's (256,2) made regalloc
// target 4 waves/SIMD -> it capped at 128 VGPR and spilled ~80 of the ~208
// live values (m[64]+cur[64]+spk[64]+misc) to scratch; FETCH_SIZE showed
// ~875 MB of scratch churn. min-waves=1 gives a 512-VGPR budget so the whole
// state fits in registers; 64 independent h-chains give enough ILP to keep
// the fp32 pipe fed at 2 waves/SIMD.
// Arithmetic order is bit-identical to the passing round-2 kernel:
//   m = rn(rn(rn(0.95*m) + cur) - spk); spk = (m>1) ? 1 : 0
//   cur2 accumulated over h=0..63 by sequential fma; +b2 as separate add.
__global__ __launch_bounds__(256, 1) void snn_fused(
    const float* __restrict__ x,
    const float* __restrict__ W1,
    const float* __restrict__ b1,
    const float* __restrict__ W2,
    const float* __restrict__ b2,
    float* __restrict__ out)
{
    const int b = blockIdx.x * 256 + threadIdx.x;
    const float2 xv = reinterpret_cast<const float2*>(x)[b];

    float cur[HID], m[HID], spk[HID];
#pragma unroll
    for (int h = 0; h < HID; ++h) {
        // cur1_h = rn(fma(x1,w11, rn(x0*w10)) + b1[h])  (same as rounds 1-2)
        float c = __fmul_rn(xv.x, W1[2 * h + 0]);
        c = __builtin_fmaf(xv.y, W1[2 * h + 1], c);
        cur[h] = __fadd_rn(c, b1[h]);
        m[h] = 0.0f;
        spk[h] = 0.0f;
    }

    const float bb0 = b2[0], bb1 = b2[1];
    float m0 = 0.0f, m1 = 0.0f, s0 = 0.0f, s1 = 0.0f;
    float2* outspk = reinterpret_cast<float2*>(out) + b;                         // [t][b][2]
    float2* outmem = reinterpret_cast<float2*>(out) + (size_t)NSTEP * BATCH + b;

#pragma unroll 1
    for (int t = 0; t < NSTEP; ++t) {
        float a0 = 0.0f, a1 = 0.0f;
#pragma unroll
        for (int h = 0; h < HID; ++h) {
            // LIF layer 1, exact rounded-op order; spk[h] is spike(t-1) == reset(t)
            m[h] = __fsub_rn(__fadd_rn(__fmul_rn(0.95f, m[h]), cur[h]), spk[h]);
            spk[h] = (m[h] > 1.0f) ? 1.0f : 0.0f;
            // cur2 partial sums, sequential-h fma order
            a0 = __builtin_fmaf(spk[h], W2[h], a0);        // W2[0][h]
            a1 = __builtin_fmaf(spk[h], W2[HID + h], a1);  // W2[1][h]
        }
        // LIF layer 2 + coalesced interleaved stores
        const float c0 = __fadd_rn(a0, bb0);
        const float c1 = __fadd_rn(a1, bb1);
        m0 = __fsub_rn(__fadd_rn(__fmul_rn(0.95f, m0), c0), s0);
        m1 = __fsub_rn(__fadd_rn(__fmul_rn(0.95f, m1), c1), s1);
        s0 = (m0 > 1.0f) ? 1.0f : 0.0f;
        s1 = (m1 > 1.0f) ? 1.0f : 0.0f;
        outspk[(size_t)t * BATCH] = make_float2(s0, s1);
        outmem[(size_t)t * BATCH] = make_float2(m0, m1);
    }
}

extern "C" void kernel_launch(void* const* d_in, const int* in_sizes, int n_in,
                              void* d_out, int out_size, void* d_ws, size_t ws_size,
                              hipStream_t stream)
{
    const float* x  = (const float*)d_in[0];
    const float* W1 = (const float*)d_in[1];
    const float* b1 = (const float*)d_in[2];
    const float* W2 = (const float*)d_in[3];
    const float* b2 = (const float*)d_in[4];
    float* out = (float*)d_out;
    snn_fused<<<BATCH / 256, 256, 0, stream>>>(x, W1, b1, W2, b2, out);
}

// Round 4
// 133.370 us; speedup vs baseline: 1.0781x; 1.0781x over previous
//
#include <hip/hip_runtime.h>

#define BATCH 262144
#define NSTEP 50

// One thread per batch element, t-outer / h-inner.
// Round-4 change: the h-state lives in 192 NAMED scalar variables generated
// by macro expansion instead of float arrays. Rounds 1-3 all kept the arrays
// in scratch (VGPR 56/128/132 with ~1.1 GB FETCH_SIZE of L2-missing scratch
// churn): SROA runs before loop unrolling, sees variable-indexed allocas, and
// nothing re-promotes them post-unroll. Named scalars can't be allocas.
// ~212 VGPR demand fits the 256-VGPR cap of __launch_bounds__(256,2)
// -> 2 waves/SIMD, 64 independent h-chains of ILP per thread.
// Arithmetic order bit-identical to rounds 1-3 (absmax must stay 0.0078125):
//   m = rn(rn(rn(0.95*m) + cur) - s); s = (m>1) ? 1 : 0
//   a0/a1 accumulate h=0..63 by sequential fma; +b2 as separate rounded add.

#define H64(F) F(0) F(1) F(2) F(3) F(4) F(5) F(6) F(7) \
  F(8) F(9) F(10) F(11) F(12) F(13) F(14) F(15) \
  F(16) F(17) F(18) F(19) F(20) F(21) F(22) F(23) \
  F(24) F(25) F(26) F(27) F(28) F(29) F(30) F(31) \
  F(32) F(33) F(34) F(35) F(36) F(37) F(38) F(39) \
  F(40) F(41) F(42) F(43) F(44) F(45) F(46) F(47) \
  F(48) F(49) F(50) F(51) F(52) F(53) F(54) F(55) \
  F(56) F(57) F(58) F(59) F(60) F(61) F(62) F(63)

__global__ __launch_bounds__(256, 2) void snn_fused(
    const float* __restrict__ x,
    const float* __restrict__ W1,
    const float* __restrict__ b1,
    const float* __restrict__ W2,
    const float* __restrict__ b2,
    float* __restrict__ out)
{
    const int b = blockIdx.x * 256 + threadIdx.x;
    const float2 xv = reinterpret_cast<const float2*>(x)[b];
    const float2* __restrict__ W1v = reinterpret_cast<const float2*>(W1);

    // cur1_h = rn(fma(x1,w11, rn(x0*w10)) + b1[h])  (same as rounds 1-3)
#define DECL(i)                                             \
    float cur##i, m##i = 0.0f, s##i = 0.0f;                 \
    {                                                       \
        const float2 w = W1v[i];                            \
        float c = __fmul_rn(xv.x, w.x);                     \
        c = __builtin_fmaf(xv.y, w.y, c);                   \
        cur##i = __fadd_rn(c, b1[i]);                       \
    }
    H64(DECL)
#undef DECL

    const float bb0 = b2[0], bb1 = b2[1];
    float m0o = 0.0f, m1o = 0.0f, s0o = 0.0f, s1o = 0.0f;
    float2* outspk = reinterpret_cast<float2*>(out) + b;                         // [t][b][2]
    float2* outmem = reinterpret_cast<float2*>(out) + (size_t)NSTEP * BATCH + b;

#pragma unroll 1
    for (int t = 0; t < NSTEP; ++t) {
        float a0 = 0.0f, a1 = 0.0f;
        // LIF layer 1 (exact rounded-op order; s##i is spike(t-1) == reset(t))
        // + sequential-h fma accumulation of cur2 partials.
#define STEP(i)                                                               \
        m##i = __fsub_rn(__fadd_rn(__fmul_rn(0.95f, m##i), cur##i), s##i);    \
        s##i = (m##i > 1.0f) ? 1.0f : 0.0f;                                   \
        a0 = __builtin_fmaf(s##i, W2[i], a0);                                 \
        a1 = __builtin_fmaf(s##i, W2[64 + i], a1);
        H64(STEP)
#undef STEP

        // LIF layer 2 + coalesced interleaved stores
        const float c0 = __fadd_rn(a0, bb0);
        const float c1 = __fadd_rn(a1, bb1);
        m0o = __fsub_rn(__fadd_rn(__fmul_rn(0.95f, m0o), c0), s0o);
        m1o = __fsub_rn(__fadd_rn(__fmul_rn(0.95f, m1o), c1), s1o);
        s0o = (m0o > 1.0f) ? 1.0f : 0.0f;
        s1o = (m1o > 1.0f) ? 1.0f : 0.0f;
        outspk[(size_t)t * BATCH] = make_float2(s0o, s1o);
        outmem[(size_t)t * BATCH] = make_float2(m0o, m1o);
    }
}

extern "C" void kernel_launch(void* const* d_in, const int* in_sizes, int n_in,
                              void* d_out, int out_size, void* d_ws, size_t ws_size,
                              hipStream_t stream)
{
    const float* x  = (const float*)d_in[0];
    const float* W1 = (const float*)d_in[1];
    const float* b1 = (const float*)d_in[2];
    const float* W2 = (const float*)d_in[3];
    const float* b2 = (const float*)d_in[4];
    float* out = (float*)d_out;
    snn_fused<<<BATCH / 256, 256, 0, stream>>>(x, W1, b1, W2, b2, out);
}

// Round 6
// 131.927 us; speedup vs baseline: 1.0899x; 1.0109x over previous
//
#include <hip/hip_runtime.h>

#define BATCH 262144
#define NSTEP 50

// One thread per batch element, t-outer / h-inner, state in 192 NAMED scalars
// (macro-expanded) -> all registers, no allocas (r4 structure, proven).
// Round-6 change vs r4: t-loop unrolled x2. Step t+1's 64 independent LIF
// chains depend only on m(t) -> they can fill the stalls of step t's serial
// layer-2 tail + stores + W2 s_load waits; unroll exposes this cross-step ILP
// to the scheduler. Register state unchanged -> same occupancy.
// r5 lesson: ANY reordering of the cur2 fma fold flips an output spike
// (absmax 1.0). Arithmetic below is BIT-IDENTICAL to the passing r4:
//   m = rn(rn(rn(0.95*m) + cur) - s); s = (m>1) ? 1 : 0
//   a0/a1 accumulate h=0..63 by sequential fma; +b2 as separate rounded add.
// No packed fp32: CDNA4 fp32 peak (157.3 TF) = scalar rate x max clock;
// v_pk_*_f32 is 2 data-path passes -- we are data-path-bound (118 us busy at
// the measured 1.57 GHz sustained VALU clock), so pk gains nothing.

#define H64(F) F(0) F(1) F(2) F(3) F(4) F(5) F(6) F(7) \
  F(8) F(9) F(10) F(11) F(12) F(13) F(14) F(15) \
  F(16) F(17) F(18) F(19) F(20) F(21) F(22) F(23) \
  F(24) F(25) F(26) F(27) F(28) F(29) F(30) F(31) \
  F(32) F(33) F(34) F(35) F(36) F(37) F(38) F(39) \
  F(40) F(41) F(42) F(43) F(44) F(45) F(46) F(47) \
  F(48) F(49) F(50) F(51) F(52) F(53) F(54) F(55) \
  F(56) F(57) F(58) F(59) F(60) F(61) F(62) F(63)

__global__ __launch_bounds__(256, 2) void snn_fused(
    const float* __restrict__ x,
    const float* __restrict__ W1,
    const float* __restrict__ b1,
    const float* __restrict__ W2,
    const float* __restrict__ b2,
    float* __restrict__ out)
{
    const int b = blockIdx.x * 256 + threadIdx.x;
    const float2 xv = reinterpret_cast<const float2*>(x)[b];
    const float2* __restrict__ W1v = reinterpret_cast<const float2*>(W1);

    // cur1_h = rn(fma(x1,w1h1, rn(x0*w1h0)) + b1[h])  (identical to r1-r4)
#define DECL(i)                                             \
    float cur##i, m##i = 0.0f, s##i = 0.0f;                 \
    {                                                       \
        const float2 w = W1v[i];                            \
        float c = __fmul_rn(xv.x, w.x);                     \
        c = __builtin_fmaf(xv.y, w.y, c);                   \
        cur##i = __fadd_rn(c, b1[i]);                       \
    }
    H64(DECL)
#undef DECL

    const float bb0 = b2[0], bb1 = b2[1];
    float m0o = 0.0f, m1o = 0.0f, s0o = 0.0f, s1o = 0.0f;
    float2* outspk = reinterpret_cast<float2*>(out) + b;                         // [t][b][2]
    float2* outmem = reinterpret_cast<float2*>(out) + (size_t)NSTEP * BATCH + b;

#pragma unroll 2
    for (int t = 0; t < NSTEP; ++t) {
        float a0 = 0.0f, a1 = 0.0f;
        // LIF layer 1 (exact rounded-op order; s##i is spike(t-1) == reset(t))
        // + sequential-h fma accumulation of cur2 partials (order sacred).
#define STEP(i)                                                               \
        m##i = __fsub_rn(__fadd_rn(__fmul_rn(0.95f, m##i), cur##i), s##i);    \
        s##i = (m##i > 1.0f) ? 1.0f : 0.0f;                                   \
        a0 = __builtin_fmaf(s##i, W2[i], a0);                                 \
        a1 = __builtin_fmaf(s##i, W2[64 + i], a1);
        H64(STEP)
#undef STEP

        // LIF layer 2 + coalesced interleaved stores
        const float c0 = __fadd_rn(a0, bb0);
        const float c1 = __fadd_rn(a1, bb1);
        m0o = __fsub_rn(__fadd_rn(__fmul_rn(0.95f, m0o), c0), s0o);
        m1o = __fsub_rn(__fadd_rn(__fmul_rn(0.95f, m1o), c1), s1o);
        s0o = (m0o > 1.0f) ? 1.0f : 0.0f;
        s1o = (m1o > 1.0f) ? 1.0f : 0.0f;
        outspk[(size_t)t * BATCH] = make_float2(s0o, s1o);
        outmem[(size_t)t * BATCH] = make_float2(m0o, m1o);
    }
}

extern "C" void kernel_launch(void* const* d_in, const int* in_sizes, int n_in,
                              void* d_out, int out_size, void* d_ws, size_t ws_size,
                              hipStream_t stream)
{
    const float* x  = (const float*)d_in[0];
    const float* W1 = (const float*)d_in[1];
    const float* b1 = (const float*)d_in[2];
    const float* W2 = (const float*)d_in[3];
    const float* b2 = (const float*)d_in[4];
    float* out = (float*)d_out;
    snn_fused<<<BATCH / 256, 256, 0, stream>>>(x, W1, b1, W2, b2, out);
}